// Round 2
// baseline (1136.828 us; speedup 1.0000x reference)
//
#include <hip/hip_runtime.h>
#include <hip/hip_bf16.h>
#include <stdint.h>

// Problem constants (from reference): B=8,S=2048,IN=4096,OUT=4096,G=32
#define M_TOT 16384   // B*S
#define N_TOT 4096    // OUT
#define K_TOT 4096    // IN
#define NB    524288  // OUT*IN/G
#define BM 128
#define BN 128
#define BK 32

typedef __attribute__((ext_vector_type(8))) __bf16 bf16x8;
typedef __attribute__((ext_vector_type(4))) float f32x4;

// ---------------------------------------------------------------------------
// Kernel 1: dequantize int4-packed W -> bf16 [OUT, IN] row-major.
// One thread handles 4 packed int32 (one int4 load) -> 8 bf16 (one 16B store).
// Value interleave per reference: int j in block -> values 2j (lo), 2j+1 (hi).
// NOTE round 1 post-mortem: harness wire dtypes are {bf16, f32, int32} only.
// fp16 scale arrives promoted to f32; bool mask arrives as int32. Reading
// scale as __half caused the 230k absmax blowup.
// ---------------------------------------------------------------------------
__global__ __launch_bounds__(256) void dequant_w(
    const int* __restrict__ packed,          // [NB, 16] int32, one byte each
    const float* __restrict__ scale,         // [NB] f32 (promoted from fp16)
    const int* __restrict__ mask,            // [NB] int32 (promoted from bool)
    __hip_bfloat16* __restrict__ wout)       // [OUT*IN] bf16
{
    int t = blockIdx.x * blockDim.x + threadIdx.x;   // 0 .. NB*4-1
    const int4 pk = ((const int4*)packed)[t];
    int nb = t >> 2;
    float se = scale[nb] * (mask[nb] ? 1.0f : 0.5f);
    int vals[4] = { pk.x, pk.y, pk.z, pk.w };
    __hip_bfloat16 o[8];
#pragma unroll
    for (int j = 0; j < 4; ++j) {
        int v = vals[j];
        o[2*j]   = __float2bfloat16((float)((v & 0xF) - 8) * se);
        o[2*j+1] = __float2bfloat16((float)(((v >> 4) & 0xF) - 8) * se);
    }
    int4 st;
    __builtin_memcpy(&st, o, 16);
    ((int4*)wout)[t] = st;
}

// ---------------------------------------------------------------------------
// Kernel 2: x fp32 -> bf16. One thread: 2 float4 loads -> 8 bf16 (16B store).
// ---------------------------------------------------------------------------
__global__ __launch_bounds__(256) void cvt_x(
    const float* __restrict__ x, __hip_bfloat16* __restrict__ xb)
{
    int t = blockIdx.x * blockDim.x + threadIdx.x;   // each handles 8 elems
    const float4* xp = (const float4*)x;
    float4 a = xp[2*t], b = xp[2*t + 1];
    __hip_bfloat16 o[8] = {
        __float2bfloat16(a.x), __float2bfloat16(a.y),
        __float2bfloat16(a.z), __float2bfloat16(a.w),
        __float2bfloat16(b.x), __float2bfloat16(b.y),
        __float2bfloat16(b.z), __float2bfloat16(b.w)
    };
    int4 st;
    __builtin_memcpy(&st, o, 16);
    ((int4*)xb)[t] = st;
}

// ---------------------------------------------------------------------------
// Kernel 3: C[M,N] = A[M,K] * W[N,K]^T + bias. m97 structure:
// 128x128 tile, BK=32, 4 waves (2x2), each wave 4x4 tiles of 16x16x32 bf16
// MFMA. global_load_lds width=16, lane-linear LDS (no padding: wave-uniform
// base + lane*16 semantics). Two-barrier K-loop.
// ---------------------------------------------------------------------------
__global__ __launch_bounds__(256) void gemm_bt(
    const __hip_bfloat16* __restrict__ A,   // [M_TOT, K_TOT] bf16
    const __hip_bfloat16* __restrict__ Bw,  // [N_TOT, K_TOT] bf16
    const float* __restrict__ bias,         // [N_TOT]
    float* __restrict__ C)                  // [M_TOT, N_TOT]
{
    __shared__ __hip_bfloat16 As[BM * BK];  // 8 KB
    __shared__ __hip_bfloat16 Bs[BN * BK];  // 8 KB

    const int tid  = threadIdx.x;
    const int lane = tid & 63;
    const int wave = tid >> 6;
    const int wm = wave >> 1;   // 0..1
    const int wn = wave & 1;    // 0..1

    // GROUP_M=8 swizzle: 256 consecutive blocks share 8 M-tiles x all 32
    // N-tiles -> W (32MB) + 8MB of x stay hot in L2/L3 per dispatch wave.
    const int num_n = N_TOT / BN;           // 32
    const int GROUP_M = 8;
    int pid        = blockIdx.x;
    int group_size = GROUP_M * num_n;       // 256
    int group      = pid / group_size;
    int within     = pid - group * group_size;
    int mt         = group * GROUP_M + (within % GROUP_M);
    int nt         = within / GROUP_M;
    const int m0 = mt * BM;
    const int n0 = nt * BN;

    // Staging: row = tid/4 (64 rows/issue, 2 issues = 128), chunk = tid%4
    // (16B chunks of the 64B k-row). LDS dest is lane-linear: tid*16 bytes.
    const int srow = tid >> 2;
    const int sch  = tid & 3;
    const char* gA0 = (const char*)(A  + (size_t)(m0 + srow)      * K_TOT) + sch * 16;
    const char* gA1 = (const char*)(A  + (size_t)(m0 + 64 + srow) * K_TOT) + sch * 16;
    const char* gB0 = (const char*)(Bw + (size_t)(n0 + srow)      * K_TOT) + sch * 16;
    const char* gB1 = (const char*)(Bw + (size_t)(n0 + 64 + srow) * K_TOT) + sch * 16;
    char* lA0 = (char*)As + tid * 16;
    char* lA1 = (char*)As + 4096 + tid * 16;
    char* lB0 = (char*)Bs + tid * 16;
    char* lB1 = (char*)Bs + 4096 + tid * 16;

    f32x4 acc[4][4] = {};

    // Fragment addressing: A-op lane l holds A[m=l&15][k=(l>>4)*8 + j];
    // B-op symmetric on W rows (B^T GEMM).
    const int kfrag = (lane >> 4) * 8;
    const int rA = wm * 64 + (lane & 15);
    const int rB = wn * 64 + (lane & 15);

    for (int k0 = 0; k0 < K_TOT; k0 += BK) {
        const int kb = k0 * 2;  // byte offset along k
        __builtin_amdgcn_global_load_lds(
            (const __attribute__((address_space(1))) void*)(gA0 + kb),
            (__attribute__((address_space(3))) void*)lA0, 16, 0, 0);
        __builtin_amdgcn_global_load_lds(
            (const __attribute__((address_space(1))) void*)(gA1 + kb),
            (__attribute__((address_space(3))) void*)lA1, 16, 0, 0);
        __builtin_amdgcn_global_load_lds(
            (const __attribute__((address_space(1))) void*)(gB0 + kb),
            (__attribute__((address_space(3))) void*)lB0, 16, 0, 0);
        __builtin_amdgcn_global_load_lds(
            (const __attribute__((address_space(1))) void*)(gB1 + kb),
            (__attribute__((address_space(3))) void*)lB1, 16, 0, 0);
        __syncthreads();

        bf16x8 aF[4], bF[4];
#pragma unroll
        for (int i = 0; i < 4; ++i)
            aF[i] = *(const bf16x8*)(As + (rA + i * 16) * BK + kfrag);
#pragma unroll
        for (int j = 0; j < 4; ++j)
            bF[j] = *(const bf16x8*)(Bs + (rB + j * 16) * BK + kfrag);

#pragma unroll
        for (int i = 0; i < 4; ++i)
#pragma unroll
            for (int j = 0; j < 4; ++j)
                acc[i][j] = __builtin_amdgcn_mfma_f32_16x16x32_bf16(
                    aF[i], bF[j], acc[i][j], 0, 0, 0);

        __syncthreads();
    }

    // Epilogue: C/D layout col=lane&15, row=(lane>>4)*4+reg (m89-verified).
    const int col_l = lane & 15;
    const int row_q = (lane >> 4) * 4;
#pragma unroll
    for (int j = 0; j < 4; ++j) {
        const int col = n0 + wn * 64 + j * 16 + col_l;
        const float bv = bias[col];
#pragma unroll
        for (int i = 0; i < 4; ++i) {
            const int rbase = m0 + wm * 64 + i * 16 + row_q;
#pragma unroll
            for (int r = 0; r < 4; ++r) {
                C[(size_t)(rbase + r) * N_TOT + col] = acc[i][j][r] + bv;
            }
        }
    }
}

// ---------------------------------------------------------------------------
extern "C" void kernel_launch(void* const* d_in, const int* in_sizes, int n_in,
                              void* d_out, int out_size, void* d_ws, size_t ws_size,
                              hipStream_t stream) {
    const float* x      = (const float*)d_in[0];
    const int*   wp     = (const int*)d_in[1];
    const float* wscale = (const float*)d_in[2];   // fp16 promoted to f32 by harness
    const int*   wmask  = (const int*)d_in[3];     // bool promoted to int32
    const float* bias   = (const float*)d_in[4];
    float*       out    = (float*)d_out;

    // Workspace: W bf16 (32 MB) at offset 0, x bf16 (128 MB) after.
    __hip_bfloat16* Wb = (__hip_bfloat16*)d_ws;
    __hip_bfloat16* Xb = (__hip_bfloat16*)((char*)d_ws + (size_t)N_TOT * K_TOT * 2);

    // 1) dequant W: NB*4 threads
    dequant_w<<<(NB * 4) / 256, 256, 0, stream>>>(wp, wscale, wmask, Wb);
    // 2) convert x: M*K/8 threads
    cvt_x<<<((size_t)M_TOT * K_TOT / 8) / 256, 256, 0, stream>>>(x, Xb);
    // 3) GEMM: 128 x 32 tiles
    gemm_bt<<<(M_TOT / BM) * (N_TOT / BN), 256, 0, stream>>>(Xb, Wb, bias, out);
}